// Round 13
// baseline (57.806 us; speedup 1.0000x reference)
//
#include <hip/hip_runtime.h>
#include <hip/hip_bf16.h>

// RBF kernel matrix: out[i][j] = exp(-gamma * max(x2[i] + y2[j] - 2*x.y, 0))
//
// Round 13: r12 (fenced 16-sub-tile store interleave, 56.2us) + SPLIT-STAGE
// early start. DMA issue order: XH,YH then XL,YL; s_waitcnt vmcnt(8) + raw
// s_barrier -> hoist hi frags and run the full hi*hi pass (32 MFMAs) WHILE
// the lo DMA is in flight; then __syncthreads (its vmcnt(0) drain == XL/YL
// wait, no stores outstanding yet), hoist lo frags, and run 16 fenced
// sub-tiles (4 correction MFMAs + 4 exp + 1 float4 store each).
// Shrinks the store-idle block prologue ~2x (the residual vs the 39us
// write floor after r11/r12 established burst-smoothing as the lever).
// 3 MFMA passes total (hi*hi + loY*hiX + hiY*loX), drop lo*lo (~1e-21 err).

#define DD 64
#define BM 128
#define BN 128

typedef __attribute__((ext_vector_type(8))) short short8;
typedef __attribute__((ext_vector_type(4))) float f32x4;

#if __has_builtin(__builtin_amdgcn_exp2f)
#define EXP2(x) __builtin_amdgcn_exp2f(x)
#else
#define EXP2(x) exp2f(x)
#endif

__device__ __forceinline__ unsigned short f2bf_rne(float f) {
  unsigned u = __float_as_uint(f);
  unsigned r = u + 0x7FFFu + ((u >> 16) & 1u);
  return (unsigned short)(r >> 16);
}

// ---------------- prep: fp32 norms + bf16 hi/lo pre-split (pre-swizzled) ----
__global__ __launch_bounds__(256)
void prep_split(const float* __restrict__ X, const float* __restrict__ Y,
                unsigned short* __restrict__ XHg, unsigned short* __restrict__ XLg,
                unsigned short* __restrict__ YHg, unsigned short* __restrict__ YLg,
                float* __restrict__ xsq, float* __restrict__ ysq, int n) {
  int t = blockIdx.x * 256 + threadIdx.x;
  int row = t >> 4;       // 16 lanes per row
  int c4 = t & 15;        // float4 index within row
  const float* src;
  unsigned short *hd, *ld;
  float* nd;
  int r;
  if (row < n) { r = row;     src = X + (long)r * DD; hd = XHg; ld = XLg; nd = xsq + r; }
  else         { r = row - n; src = Y + (long)r * DD; hd = YHg; ld = YLg; nd = ysq + r; }
  float4 v = ((const float4*)src)[c4];
  float f[4] = {v.x, v.y, v.z, v.w};
  unsigned short h[4], l[4];
#pragma unroll
  for (int q = 0; q < 4; ++q) {
    h[q] = f2bf_rne(f[q]);
    float hv = __uint_as_float(((unsigned)h[q]) << 16);
    l[q] = f2bf_rne(f[q] - hv);
  }
  int sw = (c4 * 8) ^ ((r & 7) << 4);   // swizzled byte offset within 128-B row
  *(ushort4*)((char*)hd + (long)r * 128 + sw) = make_ushort4(h[0], h[1], h[2], h[3]);
  *(ushort4*)((char*)ld + (long)r * 128 + sw) = make_ushort4(l[0], l[1], l[2], l[3]);
  float s = v.x * v.x + v.y * v.y + v.z * v.z + v.w * v.w;
  s += __shfl_xor(s, 1);
  s += __shfl_xor(s, 2);
  s += __shfl_xor(s, 4);
  s += __shfl_xor(s, 8);
  if (c4 == 0) *nd = s;
}

// ---------------- main: split-stage + hh-pass overlap + fenced sub-tiles ----
__global__ __launch_bounds__(256, 2)
void rbf_pipe(const unsigned short* __restrict__ XHg, const unsigned short* __restrict__ XLg,
              const unsigned short* __restrict__ YHg, const unsigned short* __restrict__ YLg,
              const float* __restrict__ gptr,
              const float* __restrict__ xsq, const float* __restrict__ ysq,
              float* __restrict__ Out, int mcols) {
  // [0,16K) XH  [16K,32K) XL  [32K,48K) YH  [48K,64K) YL (swizzled images)
  __shared__ __align__(128) char lds[65536];

  const int tid = threadIdx.x;
  const int lane = tid & 63;
  const int wid = tid >> 6;        // 0..3
  const long i0 = (long)blockIdx.y * BM;
  const long j0 = (long)blockIdx.x * BN;

  // ---- stage: issue order XH, YH, XL, YL (4 loads each per thread)
  const char* srcs[4] = {(const char*)XHg + i0 * 128,   // -> lds + 0
                         (const char*)YHg + j0 * 128,   // -> lds + 32K
                         (const char*)XLg + i0 * 128,   // -> lds + 16K
                         (const char*)YLg + j0 * 128};  // -> lds + 48K
  const int dsts[4] = {0, 32768, 16384, 49152};
#pragma unroll
  for (int t4 = 0; t4 < 4; ++t4) {
#pragma unroll
    for (int it = 0; it < 4; ++it) {
      int off = it * 4096 + wid * 1024;           // wave-uniform
      const char* g = srcs[t4] + off + lane * 16; // per-lane global src
      __builtin_amdgcn_global_load_lds(
          (const __attribute__((address_space(1))) void*)g,
          (__attribute__((address_space(3))) void*)(lds + dsts[t4] + off),
          16, 0, 0);
    }
  }

  // ---- wait only for XH+YH (oldest 8 of 16), then converge
  asm volatile("s_waitcnt vmcnt(8)" ::: "memory");
  __builtin_amdgcn_s_barrier();

  const int wr = wid >> 1, wc = wid & 1;
  const int lr = lane & 15;
  const int hg = lane >> 4;        // 0..3

  // ---- hoist hi fragments, run hi*hi pass while lo DMA is in flight
  short8 afh[2][4], bfh[2][4];     // [s][q]
#pragma unroll
  for (int s = 0; s < 2; ++s)
#pragma unroll
    for (int q = 0; q < 4; ++q) {
      int ra = wr * 64 + q * 16 + lr;
      int oa = (s * 64 + hg * 16) ^ ((ra & 7) << 4);
      afh[s][q] = *(const short8*)(lds + ra * 128 + oa);
      int rb = wc * 64 + q * 16 + lr;
      int ob = (s * 64 + hg * 16) ^ ((rb & 7) << 4);
      bfh[s][q] = *(const short8*)(lds + 32768 + rb * 128 + ob);
    }

  // norms/gamma fetch overlaps the hh pass
  const float g = *gptr;
  const float cf = -g * 1.4426950408889634f;   // -gamma*log2(e)
  const float nc2 = -2.0f * cf;
  float cxr[4];
#pragma unroll
  for (int m2 = 0; m2 < 4; ++m2) cxr[m2] = cf * xsq[i0 + wr * 64 + m2 * 16 + lr];
  float4 cyv[4];
#pragma unroll
  for (int n2 = 0; n2 < 4; ++n2) {
    float4 yq = *(const float4*)&ysq[j0 + wc * 64 + n2 * 16 + hg * 4];
    cyv[n2] = make_float4(cf * yq.x, cf * yq.y, cf * yq.z, cf * yq.w);
  }

  f32x4 acc[4][4];
#pragma unroll
  for (int a = 0; a < 4; ++a)
#pragma unroll
    for (int c = 0; c < 4; ++c) acc[a][c] = (f32x4){0.f, 0.f, 0.f, 0.f};

#pragma unroll
  for (int s = 0; s < 2; ++s)
#pragma unroll
    for (int m2 = 0; m2 < 4; ++m2)
#pragma unroll
      for (int n2 = 0; n2 < 4; ++n2)
        acc[m2][n2] = __builtin_amdgcn_mfma_f32_16x16x32_bf16(bfh[s][n2], afh[s][m2], acc[m2][n2], 0, 0, 0);

  // ---- XL/YL now needed: __syncthreads drains vmcnt(0) (no stores yet)
  __syncthreads();

  short8 afl[2][4], bfl[2][4];
#pragma unroll
  for (int s = 0; s < 2; ++s)
#pragma unroll
    for (int q = 0; q < 4; ++q) {
      int ra = wr * 64 + q * 16 + lr;
      int oa = (s * 64 + hg * 16) ^ ((ra & 7) << 4);
      afl[s][q] = *(const short8*)(lds + 16384 + ra * 128 + oa);
      int rb = wc * 64 + q * 16 + lr;
      int ob = (s * 64 + hg * 16) ^ ((rb & 7) << 4);
      bfl[s][q] = *(const short8*)(lds + 49152 + rb * 128 + ob);
    }

  // ---- 16 fenced sub-tiles: 4 correction MFMAs + 4 exp + 1 store each
#pragma unroll
  for (int m2 = 0; m2 < 4; ++m2) {
    long row = i0 + wr * 64 + m2 * 16 + lr;
    float* op = Out + row * (long)mcols + j0 + wc * 64 + hg * 4;
#pragma unroll
    for (int n2 = 0; n2 < 4; ++n2) {
      f32x4 a = acc[m2][n2];
#pragma unroll
      for (int s = 0; s < 2; ++s) {
        a = __builtin_amdgcn_mfma_f32_16x16x32_bf16(bfh[s][n2], afl[s][m2], a, 0, 0, 0);
        a = __builtin_amdgcn_mfma_f32_16x16x32_bf16(bfl[s][n2], afh[s][m2], a, 0, 0, 0);
      }
      float cy[4] = {cyv[n2].x, cyv[n2].y, cyv[n2].z, cyv[n2].w};
      float o[4];
#pragma unroll
      for (int j = 0; j < 4; ++j)
        o[j] = EXP2(fminf(fmaf(nc2, a[j], cxr[m2] + cy[j]), 0.f));
      *(float4*)(op + n2 * 16) = *(float4*)o;
      __builtin_amdgcn_sched_barrier(0);   // pin: keep stores evenly spaced
    }
  }
}

// ---------------- fallback (proven round-2 path) ---------------------------
__global__ __launch_bounds__(256)
void prep_sq(const float* __restrict__ X, const float* __restrict__ Y,
             float* __restrict__ xsq, float* __restrict__ ysq, int n) {
  int t = blockIdx.x * 256 + threadIdx.x;
  int row = t >> 4;
  int c = t & 15;
  const float* src;
  float* dst;
  if (row < n) { src = X + (long)row * DD; dst = xsq + row; }
  else         { src = Y + (long)(row - n) * DD; dst = ysq + (row - n); }
  float4 v = ((const float4*)src)[c];
  float s = v.x * v.x + v.y * v.y + v.z * v.z + v.w * v.w;
  s += __shfl_xor(s, 1);
  s += __shfl_xor(s, 2);
  s += __shfl_xor(s, 4);
  s += __shfl_xor(s, 8);
  if (c == 0) *dst = s;
}

__global__ __launch_bounds__(256, 2)
void rbf_mfma_fb(const float* __restrict__ X, const float* __restrict__ Y,
                 const float* __restrict__ gptr,
                 const float* __restrict__ xsq, const float* __restrict__ ysq,
                 float* __restrict__ Out, int mcols) {
  __shared__ unsigned short XH[128 * DD], XL[128 * DD];
  __shared__ unsigned short YH[128 * DD], YL[128 * DD];
  const int tid = threadIdx.x;
  const long i0 = (long)blockIdx.y * 128;
  const long j0 = (long)blockIdx.x * 128;
#pragma unroll
  for (int it = 0; it < 16; ++it) {
    int e = it * 256 + tid;
    int half = e >> 11;
    int idx = e & 2047;
    int row = idx >> 4;
    int c4 = idx & 15;
    const float* src = half ? (Y + (j0 + row) * DD) : (X + (i0 + row) * DD);
    float4 v = ((const float4*)src)[c4];
    float f[4] = {v.x, v.y, v.z, v.w};
    unsigned short h[4], l[4];
#pragma unroll
    for (int q = 0; q < 4; ++q) {
      h[q] = f2bf_rne(f[q]);
      float hv = __uint_as_float(((unsigned)h[q]) << 16);
      l[q] = f2bf_rne(f[q] - hv);
    }
    int sw = (c4 * 8) ^ ((row & 7) << 4);
    unsigned short* Ht = half ? YH : XH;
    unsigned short* Lt = half ? YL : XL;
    *(ushort4*)((char*)Ht + row * 128 + sw) = make_ushort4(h[0], h[1], h[2], h[3]);
    *(ushort4*)((char*)Lt + row * 128 + sw) = make_ushort4(l[0], l[1], l[2], l[3]);
  }
  __syncthreads();
  const int lane = tid & 63;
  const int wid = tid >> 6;
  const int wr = wid >> 1, wc = wid & 1;
  const int lr = lane & 15;
  const int hg = lane >> 4;
  f32x4 acc[4][4];
#pragma unroll
  for (int a = 0; a < 4; ++a)
#pragma unroll
    for (int c = 0; c < 4; ++c) acc[a][c] = (f32x4){0.f, 0.f, 0.f, 0.f};
  const unsigned short* At[3] = {XH, XL, XH};
  const unsigned short* Bt[3] = {YH, YH, YL};
#pragma unroll
  for (int p = 0; p < 3; ++p) {
#pragma unroll
    for (int s = 0; s < 2; ++s) {
      const int kbyte = s * 64 + hg * 16;
      short8 af[4], bfv[4];
#pragma unroll
      for (int m2 = 0; m2 < 4; ++m2) {
        int row = wr * 64 + m2 * 16 + lr;
        af[m2] = *(const short8*)((const char*)At[p] + row * 128 + (kbyte ^ ((row & 7) << 4)));
      }
#pragma unroll
      for (int n2 = 0; n2 < 4; ++n2) {
        int row = wc * 64 + n2 * 16 + lr;
        bfv[n2] = *(const short8*)((const char*)Bt[p] + row * 128 + (kbyte ^ ((row & 7) << 4)));
      }
#pragma unroll
      for (int m2 = 0; m2 < 4; ++m2)
#pragma unroll
        for (int n2 = 0; n2 < 4; ++n2)
          acc[m2][n2] = __builtin_amdgcn_mfma_f32_16x16x32_bf16(af[m2], bfv[n2], acc[m2][n2], 0, 0, 0);
    }
  }
  const float g = *gptr;
  float yv[4];
#pragma unroll
  for (int n2 = 0; n2 < 4; ++n2) yv[n2] = ysq[j0 + wc * 64 + n2 * 16 + lr];
#pragma unroll
  for (int m2 = 0; m2 < 4; ++m2) {
#pragma unroll
    for (int j = 0; j < 4; ++j) {
      long row = i0 + wr * 64 + m2 * 16 + hg * 4 + j;
      float xr = xsq[row];
      float* op = Out + row * (long)mcols + j0 + wc * 64 + lr;
#pragma unroll
      for (int n2 = 0; n2 < 4; ++n2) {
        float d = fmaxf(xr + yv[n2] - 2.0f * acc[m2][n2][j], 0.f);
        op[n2 * 16] = __expf(-g * d);
      }
    }
  }
}

extern "C" void kernel_launch(void* const* d_in, const int* in_sizes, int n_in,
                              void* d_out, int out_size, void* d_ws, size_t ws_size,
                              hipStream_t stream) {
  const float* x = (const float*)d_in[0];
  const float* y = (const float*)d_in[1];
  const float* g = (const float*)d_in[2];
  float* out = (float*)d_out;

  const int n = in_sizes[0] / DD;   // 8192
  const int m = in_sizes[1] / DD;   // 8192

  const size_t split_bytes = (size_t)(n + m) * DD * 2 * sizeof(unsigned short);
  const size_t needed = split_bytes + (size_t)(n + m) * sizeof(float);

  if (ws_size >= needed && (n % BM) == 0 && (m % BN) == 0) {
    unsigned short* XHg = (unsigned short*)d_ws;
    unsigned short* XLg = XHg + (size_t)n * DD;
    unsigned short* YHg = XLg + (size_t)n * DD;
    unsigned short* YLg = YHg + (size_t)m * DD;
    float* xsq = (float*)(YLg + (size_t)m * DD);
    float* ysq = xsq + n;
    prep_split<<<(n + m) / 16, 256, 0, stream>>>(x, y, XHg, XLg, YHg, YLg, xsq, ysq, n);
    dim3 grid(m / BN, n / BM);      // 64 x 64 = 4096 blocks
    rbf_pipe<<<grid, 256, 0, stream>>>(XHg, XLg, YHg, YLg, g, xsq, ysq, out, m);
  } else {
    float* xsq = (float*)d_ws;
    float* ysq = xsq + n;
    prep_sq<<<(n + m) / 16, 256, 0, stream>>>(x, y, xsq, ysq, n);
    dim3 grid2(m / 128, n / 128);
    rbf_mfma_fb<<<grid2, 256, 0, stream>>>(x, y, g, xsq, ysq, out, m);
  }
}

// Round 14
// 54.486 us; speedup vs baseline: 1.0609x; 1.0609x over previous
//
#include <hip/hip_runtime.h>
#include <hip/hip_bf16.h>

// RBF kernel matrix: out[i][j] = exp(-gamma * max(x2[i] + y2[j] - 2*x.y, 0))
//
// Round 14: r12 base (fenced 16-sub-tile interleave, 56.2us) + TWO j-tiles
// per block. The store-less prologue (stage+drain+hoist, ~1200cy, ~20% of a
// block's 5900cy write-drain share) is the residual write-pipe idle; amortize
// it over 128KB of output: stage X+Y0, hoist frags, FREE __syncthreads (no
// outstanding VM), issue Y1 DMA into the same LDS (Y0 lives in regs), tile0
// fenced sub-tiles (stores flow over the DMA), then s_waitcnt vmcnt(16) --
// the 8 DMA loads are OLDEST so this waits them, not the <=16 younger stores
// (r4's drain trap avoided) -- raw s_barrier, hoist Y1 frags, tile1 fenced
// sub-tiles. 3 MFMA passes (hh + loY*hiX + hiY*loX), drop lo*lo (~1e-21 err).

#define DD 64
#define BM 128
#define BN 128

typedef __attribute__((ext_vector_type(8))) short short8;
typedef __attribute__((ext_vector_type(4))) float f32x4;

#if __has_builtin(__builtin_amdgcn_exp2f)
#define EXP2(x) __builtin_amdgcn_exp2f(x)
#else
#define EXP2(x) exp2f(x)
#endif

__device__ __forceinline__ unsigned short f2bf_rne(float f) {
  unsigned u = __float_as_uint(f);
  unsigned r = u + 0x7FFFu + ((u >> 16) & 1u);
  return (unsigned short)(r >> 16);
}

// ---------------- prep: fp32 norms + bf16 hi/lo pre-split (pre-swizzled) ----
__global__ __launch_bounds__(256)
void prep_split(const float* __restrict__ X, const float* __restrict__ Y,
                unsigned short* __restrict__ XHg, unsigned short* __restrict__ XLg,
                unsigned short* __restrict__ YHg, unsigned short* __restrict__ YLg,
                float* __restrict__ xsq, float* __restrict__ ysq, int n) {
  int t = blockIdx.x * 256 + threadIdx.x;
  int row = t >> 4;       // 16 lanes per row
  int c4 = t & 15;        // float4 index within row
  const float* src;
  unsigned short *hd, *ld;
  float* nd;
  int r;
  if (row < n) { r = row;     src = X + (long)r * DD; hd = XHg; ld = XLg; nd = xsq + r; }
  else         { r = row - n; src = Y + (long)r * DD; hd = YHg; ld = YLg; nd = ysq + r; }
  float4 v = ((const float4*)src)[c4];
  float f[4] = {v.x, v.y, v.z, v.w};
  unsigned short h[4], l[4];
#pragma unroll
  for (int q = 0; q < 4; ++q) {
    h[q] = f2bf_rne(f[q]);
    float hv = __uint_as_float(((unsigned)h[q]) << 16);
    l[q] = f2bf_rne(f[q] - hv);
  }
  int sw = (c4 * 8) ^ ((r & 7) << 4);   // swizzled byte offset within 128-B row
  *(ushort4*)((char*)hd + (long)r * 128 + sw) = make_ushort4(h[0], h[1], h[2], h[3]);
  *(ushort4*)((char*)ld + (long)r * 128 + sw) = make_ushort4(l[0], l[1], l[2], l[3]);
  float s = v.x * v.x + v.y * v.y + v.z * v.z + v.w * v.w;
  s += __shfl_xor(s, 1);
  s += __shfl_xor(s, 2);
  s += __shfl_xor(s, 4);
  s += __shfl_xor(s, 8);
  if (c4 == 0) *nd = s;
}

// ---------------- main: 2 j-tiles per block, fenced sub-tile stores ---------
__global__ __launch_bounds__(256, 2)
void rbf_2t(const unsigned short* __restrict__ XHg, const unsigned short* __restrict__ XLg,
            const unsigned short* __restrict__ YHg, const unsigned short* __restrict__ YLg,
            const float* __restrict__ gptr,
            const float* __restrict__ xsq, const float* __restrict__ ysq,
            float* __restrict__ Out, int mcols) {
  // [0,16K) XH  [16K,32K) XL  [32K,48K) YH  [48K,64K) YL (swizzled images)
  __shared__ __align__(128) char lds[65536];

  const int tid = threadIdx.x;
  const int lane = tid & 63;
  const int wid = tid >> 6;        // 0..3
  const long i0 = (long)blockIdx.y * BM;
  const long j0 = (long)blockIdx.x * (2 * BN);   // 256-col strip

  // ---- prologue stage: XH, XL, YH(t0), YL(t0) — 16 KB each
  const char* srcs[4] = {(const char*)XHg + i0 * 128, (const char*)XLg + i0 * 128,
                         (const char*)YHg + j0 * 128, (const char*)YLg + j0 * 128};
#pragma unroll
  for (int t4 = 0; t4 < 4; ++t4) {
#pragma unroll
    for (int it = 0; it < 4; ++it) {
      int off = it * 4096 + wid * 1024;           // wave-uniform
      const char* gp = srcs[t4] + off + lane * 16;
      __builtin_amdgcn_global_load_lds(
          (const __attribute__((address_space(1))) void*)gp,
          (__attribute__((address_space(3))) void*)(lds + t4 * 16384 + off),
          16, 0, 0);
    }
  }
  __syncthreads();   // drain prologue DMA

  const int wr = wid >> 1, wc = wid & 1;
  const int lr = lane & 15;
  const int hg = lane >> 4;        // 0..3

  // ---- hoist A frags (persist both tiles) + B frags tile0
  short8 afh[2][4], afl[2][4];     // [s][m2]
  short8 bfh[2][4], bfl[2][4];     // [s][n2]
#pragma unroll
  for (int s = 0; s < 2; ++s)
#pragma unroll
    for (int q = 0; q < 4; ++q) {
      int ra = wr * 64 + q * 16 + lr;
      int oa = (s * 64 + hg * 16) ^ ((ra & 7) << 4);
      afh[s][q] = *(const short8*)(lds + ra * 128 + oa);
      afl[s][q] = *(const short8*)(lds + 16384 + ra * 128 + oa);
      int rb = wc * 64 + q * 16 + lr;
      int ob = (s * 64 + hg * 16) ^ ((rb & 7) << 4);
      bfh[s][q] = *(const short8*)(lds + 32768 + rb * 128 + ob);
      bfl[s][q] = *(const short8*)(lds + 49152 + rb * 128 + ob);
    }

  const float g = *gptr;
  const float cf = -g * 1.4426950408889634f;   // -gamma*log2(e)
  const float nc2 = -2.0f * cf;
  float cxr[4];
#pragma unroll
  for (int m2 = 0; m2 < 4; ++m2) cxr[m2] = cf * xsq[i0 + wr * 64 + m2 * 16 + lr];

  // ---- all frag ds_reads retired in all waves; nothing outstanding -> free
  __syncthreads();

  // ---- issue Y(t1) DMA into the same Y LDS region (t0 frags live in regs)
  {
    const char* yh = (const char*)YHg + (j0 + BN) * 128;
    const char* yl = (const char*)YLg + (j0 + BN) * 128;
#pragma unroll
    for (int it = 0; it < 4; ++it) {
      int off = it * 4096 + wid * 1024;
      __builtin_amdgcn_global_load_lds(
          (const __attribute__((address_space(1))) void*)(yh + off + lane * 16),
          (__attribute__((address_space(3))) void*)(lds + 32768 + off), 16, 0, 0);
      __builtin_amdgcn_global_load_lds(
          (const __attribute__((address_space(1))) void*)(yl + off + lane * 16),
          (__attribute__((address_space(3))) void*)(lds + 49152 + off), 16, 0, 0);
    }
  }

  // ---- tile 0: 16 fenced sub-tiles (6 MFMAs + 4 exp + 1 store each)
  {
    float4 cyv[4];
#pragma unroll
    for (int n2 = 0; n2 < 4; ++n2) {
      float4 yq = *(const float4*)&ysq[j0 + wc * 64 + n2 * 16 + hg * 4];
      cyv[n2] = make_float4(cf * yq.x, cf * yq.y, cf * yq.z, cf * yq.w);
    }
#pragma unroll
    for (int m2 = 0; m2 < 4; ++m2) {
      long row = i0 + wr * 64 + m2 * 16 + lr;
      float* op = Out + row * (long)mcols + j0 + wc * 64 + hg * 4;
#pragma unroll
      for (int n2 = 0; n2 < 4; ++n2) {
        f32x4 a = (f32x4){0.f, 0.f, 0.f, 0.f};
#pragma unroll
        for (int s = 0; s < 2; ++s) {
          a = __builtin_amdgcn_mfma_f32_16x16x32_bf16(bfh[s][n2], afh[s][m2], a, 0, 0, 0);
          a = __builtin_amdgcn_mfma_f32_16x16x32_bf16(bfh[s][n2], afl[s][m2], a, 0, 0, 0);
          a = __builtin_amdgcn_mfma_f32_16x16x32_bf16(bfl[s][n2], afh[s][m2], a, 0, 0, 0);
        }
        float o[4];
        o[0] = EXP2(fminf(fmaf(nc2, a[0], cxr[m2] + cyv[n2].x), 0.f));
        o[1] = EXP2(fminf(fmaf(nc2, a[1], cxr[m2] + cyv[n2].y), 0.f));
        o[2] = EXP2(fminf(fmaf(nc2, a[2], cxr[m2] + cyv[n2].z), 0.f));
        o[3] = EXP2(fminf(fmaf(nc2, a[3], cxr[m2] + cyv[n2].w), 0.f));
        *(float4*)(op + n2 * 16) = *(float4*)o;
        __builtin_amdgcn_sched_barrier(0);   // pin store spacing
      }
    }
  }

  // ---- wait ONLY the 8 Y(t1) DMA loads (oldest), not the younger stores
  asm volatile("s_waitcnt vmcnt(16)" ::: "memory");
  __builtin_amdgcn_s_barrier();     // raw barrier: no vmcnt(0) store drain

  // ---- hoist Y(t1) frags, run tile 1
#pragma unroll
  for (int s = 0; s < 2; ++s)
#pragma unroll
    for (int q = 0; q < 4; ++q) {
      int rb = wc * 64 + q * 16 + lr;
      int ob = (s * 64 + hg * 16) ^ ((rb & 7) << 4);
      bfh[s][q] = *(const short8*)(lds + 32768 + rb * 128 + ob);
      bfl[s][q] = *(const short8*)(lds + 49152 + rb * 128 + ob);
    }

  {
    const long j1 = j0 + BN;
    float4 cyv[4];
#pragma unroll
    for (int n2 = 0; n2 < 4; ++n2) {
      float4 yq = *(const float4*)&ysq[j1 + wc * 64 + n2 * 16 + hg * 4];
      cyv[n2] = make_float4(cf * yq.x, cf * yq.y, cf * yq.z, cf * yq.w);
    }
#pragma unroll
    for (int m2 = 0; m2 < 4; ++m2) {
      long row = i0 + wr * 64 + m2 * 16 + lr;
      float* op = Out + row * (long)mcols + j1 + wc * 64 + hg * 4;
#pragma unroll
      for (int n2 = 0; n2 < 4; ++n2) {
        f32x4 a = (f32x4){0.f, 0.f, 0.f, 0.f};
#pragma unroll
        for (int s = 0; s < 2; ++s) {
          a = __builtin_amdgcn_mfma_f32_16x16x32_bf16(bfh[s][n2], afh[s][m2], a, 0, 0, 0);
          a = __builtin_amdgcn_mfma_f32_16x16x32_bf16(bfh[s][n2], afl[s][m2], a, 0, 0, 0);
          a = __builtin_amdgcn_mfma_f32_16x16x32_bf16(bfl[s][n2], afh[s][m2], a, 0, 0, 0);
        }
        float o[4];
        o[0] = EXP2(fminf(fmaf(nc2, a[0], cxr[m2] + cyv[n2].x), 0.f));
        o[1] = EXP2(fminf(fmaf(nc2, a[1], cxr[m2] + cyv[n2].y), 0.f));
        o[2] = EXP2(fminf(fmaf(nc2, a[2], cxr[m2] + cyv[n2].z), 0.f));
        o[3] = EXP2(fminf(fmaf(nc2, a[3], cxr[m2] + cyv[n2].w), 0.f));
        *(float4*)(op + n2 * 16) = *(float4*)o;
        __builtin_amdgcn_sched_barrier(0);
      }
    }
  }
}

// ---------------- fallback (proven round-2 path) ---------------------------
__global__ __launch_bounds__(256)
void prep_sq(const float* __restrict__ X, const float* __restrict__ Y,
             float* __restrict__ xsq, float* __restrict__ ysq, int n) {
  int t = blockIdx.x * 256 + threadIdx.x;
  int row = t >> 4;
  int c = t & 15;
  const float* src;
  float* dst;
  if (row < n) { src = X + (long)row * DD; dst = xsq + row; }
  else         { src = Y + (long)(row - n) * DD; dst = ysq + (row - n); }
  float4 v = ((const float4*)src)[c];
  float s = v.x * v.x + v.y * v.y + v.z * v.z + v.w * v.w;
  s += __shfl_xor(s, 1);
  s += __shfl_xor(s, 2);
  s += __shfl_xor(s, 4);
  s += __shfl_xor(s, 8);
  if (c == 0) *dst = s;
}

__global__ __launch_bounds__(256, 2)
void rbf_mfma_fb(const float* __restrict__ X, const float* __restrict__ Y,
                 const float* __restrict__ gptr,
                 const float* __restrict__ xsq, const float* __restrict__ ysq,
                 float* __restrict__ Out, int mcols) {
  __shared__ unsigned short XH[128 * DD], XL[128 * DD];
  __shared__ unsigned short YH[128 * DD], YL[128 * DD];
  const int tid = threadIdx.x;
  const long i0 = (long)blockIdx.y * 128;
  const long j0 = (long)blockIdx.x * 128;
#pragma unroll
  for (int it = 0; it < 16; ++it) {
    int e = it * 256 + tid;
    int half = e >> 11;
    int idx = e & 2047;
    int row = idx >> 4;
    int c4 = idx & 15;
    const float* src = half ? (Y + (j0 + row) * DD) : (X + (i0 + row) * DD);
    float4 v = ((const float4*)src)[c4];
    float f[4] = {v.x, v.y, v.z, v.w};
    unsigned short h[4], l[4];
#pragma unroll
    for (int q = 0; q < 4; ++q) {
      h[q] = f2bf_rne(f[q]);
      float hv = __uint_as_float(((unsigned)h[q]) << 16);
      l[q] = f2bf_rne(f[q] - hv);
    }
    int sw = (c4 * 8) ^ ((row & 7) << 4);
    unsigned short* Ht = half ? YH : XH;
    unsigned short* Lt = half ? YL : XL;
    *(ushort4*)((char*)Ht + row * 128 + sw) = make_ushort4(h[0], h[1], h[2], h[3]);
    *(ushort4*)((char*)Lt + row * 128 + sw) = make_ushort4(l[0], l[1], l[2], l[3]);
  }
  __syncthreads();
  const int lane = tid & 63;
  const int wid = tid >> 6;
  const int wr = wid >> 1, wc = wid & 1;
  const int lr = lane & 15;
  const int hg = lane >> 4;
  f32x4 acc[4][4];
#pragma unroll
  for (int a = 0; a < 4; ++a)
#pragma unroll
    for (int c = 0; c < 4; ++c) acc[a][c] = (f32x4){0.f, 0.f, 0.f, 0.f};
  const unsigned short* At[3] = {XH, XL, XH};
  const unsigned short* Bt[3] = {YH, YH, YL};
#pragma unroll
  for (int p = 0; p < 3; ++p) {
#pragma unroll
    for (int s = 0; s < 2; ++s) {
      const int kbyte = s * 64 + hg * 16;
      short8 af[4], bfv[4];
#pragma unroll
      for (int m2 = 0; m2 < 4; ++m2) {
        int row = wr * 64 + m2 * 16 + lr;
        af[m2] = *(const short8*)((const char*)At[p] + row * 128 + (kbyte ^ ((row & 7) << 4)));
      }
#pragma unroll
      for (int n2 = 0; n2 < 4; ++n2) {
        int row = wc * 64 + n2 * 16 + lr;
        bfv[n2] = *(const short8*)((const char*)Bt[p] + row * 128 + (kbyte ^ ((row & 7) << 4)));
      }
#pragma unroll
      for (int m2 = 0; m2 < 4; ++m2)
#pragma unroll
        for (int n2 = 0; n2 < 4; ++n2)
          acc[m2][n2] = __builtin_amdgcn_mfma_f32_16x16x32_bf16(af[m2], bfv[n2], acc[m2][n2], 0, 0, 0);
    }
  }
  const float g = *gptr;
  float yv[4];
#pragma unroll
  for (int n2 = 0; n2 < 4; ++n2) yv[n2] = ysq[j0 + wc * 64 + n2 * 16 + lr];
#pragma unroll
  for (int m2 = 0; m2 < 4; ++m2) {
#pragma unroll
    for (int j = 0; j < 4; ++j) {
      long row = i0 + wr * 64 + m2 * 16 + hg * 4 + j;
      float xr = xsq[row];
      float* op = Out + row * (long)mcols + j0 + wc * 64 + lr;
#pragma unroll
      for (int n2 = 0; n2 < 4; ++n2) {
        float d = fmaxf(xr + yv[n2] - 2.0f * acc[m2][n2][j], 0.f);
        op[n2 * 16] = __expf(-g * d);
      }
    }
  }
}

extern "C" void kernel_launch(void* const* d_in, const int* in_sizes, int n_in,
                              void* d_out, int out_size, void* d_ws, size_t ws_size,
                              hipStream_t stream) {
  const float* x = (const float*)d_in[0];
  const float* y = (const float*)d_in[1];
  const float* g = (const float*)d_in[2];
  float* out = (float*)d_out;

  const int n = in_sizes[0] / DD;   // 8192
  const int m = in_sizes[1] / DD;   // 8192

  const size_t split_bytes = (size_t)(n + m) * DD * 2 * sizeof(unsigned short);
  const size_t needed = split_bytes + (size_t)(n + m) * sizeof(float);

  if (ws_size >= needed && (n % BM) == 0 && (m % (2 * BN)) == 0) {
    unsigned short* XHg = (unsigned short*)d_ws;
    unsigned short* XLg = XHg + (size_t)n * DD;
    unsigned short* YHg = XLg + (size_t)n * DD;
    unsigned short* YLg = YHg + (size_t)m * DD;
    float* xsq = (float*)(YLg + (size_t)m * DD);
    float* ysq = xsq + n;
    prep_split<<<(n + m) / 16, 256, 0, stream>>>(x, y, XHg, XLg, YHg, YLg, xsq, ysq, n);
    dim3 grid(m / (2 * BN), n / BM);   // 32 x 64 = 2048 blocks
    rbf_2t<<<grid, 256, 0, stream>>>(XHg, XLg, YHg, YLg, g, xsq, ysq, out, m);
  } else {
    float* xsq = (float*)d_ws;
    float* ysq = xsq + n;
    prep_sq<<<(n + m) / 16, 256, 0, stream>>>(x, y, xsq, ysq, n);
    dim3 grid2(m / 128, n / 128);
    rbf_mfma_fb<<<grid2, 256, 0, stream>>>(x, y, g, xsq, ysq, out, m);
  }
}